// Round 3
// baseline (426.764 us; speedup 1.0000x reference)
//
#include <hip/hip_runtime.h>
#include <math.h>

#define N_NODES 50000
#define N_EDGES 800000
#define D 128          // NODE_DIM
#define DE 10          // EDGE_DIM
#define WP2_ELEMS (4 * 32 * 64 * 8)  // 65536 bf16 (128x512 packed)
#define SCAN_BLOCKS 196              // 196*256 = 50176 >= 50000
#define CSTRIDE 16     // ints per histogram bin: one 64B line per node
#define ASTR 136       // bf16 per A row in node_gemm LDS
#define OST 520        // bf16 per out row in node_gemm LDS

typedef __bf16 bf16x8 __attribute__((ext_vector_type(8)));
typedef __bf16 bf16x4 __attribute__((ext_vector_type(4)));
typedef __bf16 bf16x2 __attribute__((ext_vector_type(2)));
typedef float  f32x4  __attribute__((ext_vector_type(4)));

__device__ __forceinline__ float fast_sigmoid(float x) {
    float t = __builtin_amdgcn_exp2f(-1.44269504089f * x);
    return __builtin_amdgcn_rcpf(1.0f + t);
}
__device__ __forceinline__ float fast_softplus(float x) {
    float t = __builtin_amdgcn_exp2f(-1.44269504089f * fabsf(x));
    return fmaxf(x, 0.0f) + 0.69314718056f * __builtin_amdgcn_logf(1.0f + t);
}
// bf16 pair (one u32) -> two f32
__device__ __forceinline__ float2 bf2f(unsigned int u) {
    float2 r;
    r.x = __builtin_bit_cast(float, u << 16);
    r.y = __builtin_bit_cast(float, u & 0xFFFF0000u);
    return r;
}

// ---- prep: pack node-GEMM weights | CSR histogram ----
// [0,256) wp2; [256,3381) hist.
// wp2 logical cols: 0:128=gw_top, 128:256=cw_top, 256:384=gw_mid, 384:512=cw_mid.
__global__ __launch_bounds__(256) void prep(
    const float* __restrict__ gw, const float* __restrict__ cw,
    const int* __restrict__ ei,
    __bf16* __restrict__ wp2, int* __restrict__ counts)
{
    int bx = blockIdx.x, t = threadIdx.x;
    if (bx < 256) {
        int idx = bx * 256 + t;               // < 65536
        int j    = idx & 7;
        int lane = (idx >> 3) & 63;
        int nb   = (idx >> 9) & 31;
        int kb   = idx >> 14;                 // 0..3
        int k    = kb * 32 + ((lane >> 4) << 3) + j;   // 0..127
        int jp   = nb * 16 + (lane & 15);
        float v;
        if      (jp < 128) v = gw[k * D + jp];
        else if (jp < 256) v = cw[k * D + (jp - 128)];
        else if (jp < 384) v = gw[(128 + k) * D + (jp - 256)];
        else               v = cw[(128 + k) * D + (jp - 384)];
        wp2[idx] = (__bf16)v;
    } else {
        int e = (bx - 256) * 256 + t;         // exact: 3125*256 = 800000
        atomicAdd(&counts[ei[e] * CSTRIDE], 1);
    }
}

__global__ __launch_bounds__(256) void scan_partials(
    const int* __restrict__ counts, int* __restrict__ bsum)
{
    __shared__ int ss[256];
    int t = threadIdx.x;
    int i = blockIdx.x * 256 + t;
    int c = (i < N_NODES) ? counts[i * CSTRIDE] : 0;
    ss[t] = c;
    __syncthreads();
    #pragma unroll
    for (int off = 1; off < 256; off <<= 1) {
        int v = (t >= off) ? ss[t - off] : 0;
        __syncthreads();
        ss[t] += v;
        __syncthreads();
    }
    if (t == 255) bsum[blockIdx.x] = ss[255];
}

// Writes exclusive-prefix cursor IN PLACE over counts AND a compact row_ptr.
__global__ __launch_bounds__(256) void scan_final(
    int* __restrict__ counts, const int* __restrict__ bsum,
    int* __restrict__ rp)
{
    __shared__ int sb[256];
    __shared__ int ss[256];
    int t = threadIdx.x;
    sb[t] = (t < SCAN_BLOCKS) ? bsum[t] : 0;
    int i = blockIdx.x * 256 + t;
    int c = (i < N_NODES) ? counts[i * CSTRIDE] : 0;
    ss[t] = c;
    __syncthreads();
    #pragma unroll
    for (int off = 1; off < 256; off <<= 1) {
        int v  = (t >= off) ? ss[t - off] : 0;
        int vb = (t >= off) ? sb[t - off] : 0;
        __syncthreads();
        ss[t] += v;
        sb[t] += vb;
        __syncthreads();
    }
    int base = blockIdx.x ? sb[blockIdx.x - 1] : 0;
    if (i < N_NODES) {
        int excl = base + ss[t] - c;
        counts[i * CSTRIDE] = excl;           // cursor for csr_scatter
        rp[i] = excl;                         // durable row_ptr for node_fuse
    }
    if (blockIdx.x == 0 && t == 0) rp[N_NODES] = N_EDGES;
}

// Scatter into CSR order; payload {dst, eid} (src implicit = segment owner).
__global__ __launch_bounds__(256) void csr_scatter(
    const int* __restrict__ ei, int* __restrict__ cursor,
    int2* __restrict__ sde)
{
    int e = blockIdx.x * 256 + threadIdx.x;   // grid exact: 800000
    int node = ei[e];
    int pos = atomicAdd(&cursor[node * CSTRIDE], 1);
    sde[pos] = make_int2(ei[N_EDGES + e], e);
}

// ---- node projection GEMM: [50048x128] @ [128x512] -> proj (bf16) ----
// cols 0:256 -> pa (in d_out), cols 256:512 -> pb (ws, aliases dead counts).
__global__ __launch_bounds__(512, 4) void node_gemm(
    const float* __restrict__ h, const __bf16* __restrict__ wp2,
    __bf16* __restrict__ pa, __bf16* __restrict__ pb)
{
    __shared__ __align__(16) __bf16 sm[64 * OST];   // 66,560 B; A-tile aliases base
    __bf16* za = sm;                                 // [64][ASTR] in phase A
    const int t  = threadIdx.x;
    const int r0 = blockIdx.x * 64;

    #pragma unroll
    for (int it = 0; it < 4; ++it) {
        int ch  = it * 512 + t;            // 2048 float4 chunks (64 rows x 32)
        int row = ch >> 5, cs = ch & 31;
        int node = r0 + row;
        float4 v = (node < N_NODES) ? *(const float4*)&h[(size_t)node * D + cs * 4]
                                    : make_float4(0.f, 0.f, 0.f, 0.f);
        bf16x4 o = { (__bf16)v.x, (__bf16)v.y, (__bf16)v.z, (__bf16)v.w };
        *(bf16x4*)&za[row * ASTR + cs * 4] = o;
    }
    __syncthreads();

    const int w = t >> 6, l = t & 63, quad = l >> 4, col16 = l & 15;
    f32x4 acc[4][4];
    #pragma unroll
    for (int mt = 0; mt < 4; ++mt)
        #pragma unroll
        for (int nt = 0; nt < 4; ++nt)
            acc[mt][nt] = (f32x4)0.0f;

    const __bf16* zp = &za[col16 * ASTR + quad * 8];
    const __bf16* bp = &wp2[(size_t)((w * 4) * 64 + l) * 8];

    #pragma unroll
    for (int kb = 0; kb < 4; ++kb) {
        bf16x8 afr[4];
        #pragma unroll
        for (int mt = 0; mt < 4; ++mt)
            afr[mt] = *(const bf16x8*)&zp[mt * 16 * ASTR + kb * 32];
        bf16x8 bfr[4];
        #pragma unroll
        for (int nt = 0; nt < 4; ++nt)
            bfr[nt] = *(const bf16x8*)&bp[(size_t)(kb * 32 + nt) * 512];
        #pragma unroll
        for (int mt = 0; mt < 4; ++mt)
            #pragma unroll
            for (int nt = 0; nt < 4; ++nt)
                acc[mt][nt] = __builtin_amdgcn_mfma_f32_16x16x32_bf16(
                    afr[mt], bfr[nt], acc[mt][nt], 0, 0, 0);
    }
    __syncthreads();   // A dead; reuse sm as out-tile

    #pragma unroll
    for (int mt = 0; mt < 4; ++mt)
        #pragma unroll
        for (int nt = 0; nt < 4; ++nt)
            #pragma unroll
            for (int r = 0; r < 4; ++r) {
                int row  = mt * 16 + quad * 4 + r;
                int colj = (w * 4 + nt) * 16 + col16;
                sm[row * OST + colj] = (__bf16)acc[mt][nt][r];
            }
    __syncthreads();

    #pragma unroll
    for (int it = 0; it < 8; ++it) {
        int ch  = it * 512 + t;            // 4096 chunks of 8 bf16 (64 rows x 64)
        int row = ch >> 6, cc = ch & 63;
        int node = r0 + row;
        if (node < N_NODES) {
            bf16x8 v = *(const bf16x8*)&sm[row * OST + cc * 8];
            int j0 = cc * 8;
            if (j0 < 256) *(bf16x8*)&pa[(size_t)node * 256 + j0]         = v;
            else          *(bf16x8*)&pb[(size_t)node * 256 + (j0 - 256)] = v;
        }
    }
}

// ---- node-major fused message+aggregate ----
// One wave per source node; lane owns cols (2l, 2l+1); accumulate over the
// node's CSR edge list in 2 registers; ONE plain float2 store per lane.
// No LDS, no agg atomics, no bf16 re-round of sums. ef@W_ef inlined as
// float4 FMAs with wave-uniform ef[k] (scalar loads).
__global__ __launch_bounds__(256, 6) void node_fuse(
    const __bf16* __restrict__ pa, const __bf16* __restrict__ pb,
    const int2* __restrict__ sde, const float* __restrict__ ef,
    const int* __restrict__ rp,
    const float* __restrict__ gw, const float* __restrict__ cw,
    const float* __restrict__ gb, const float* __restrict__ cb,
    float* __restrict__ agg)
{
    const int t = threadIdx.x;
    const int w = t >> 6, l = t & 63;
    const int n = blockIdx.x * 4 + w;        // 12500*4 = 50000 exact
    const int c0 = 2 * l;

    int beg = __builtin_amdgcn_readfirstlane(rp[n]);
    int end = __builtin_amdgcn_readfirstlane(rp[n + 1]);

    // own (src-side) projections, f32
    float2 ag = bf2f(*(const unsigned int*)&pa[(size_t)n * 256 + c0]);
    float2 ac = bf2f(*(const unsigned int*)&pa[(size_t)n * 256 + 128 + c0]);

    // ef weights for this lane's 2 cols, f32 direct from gw/cw rows 256..265
    float4 wk[10];
    #pragma unroll
    for (int k = 0; k < 10; ++k) {
        float2 g = *(const float2*)&gw[(size_t)(256 + k) * D + c0];
        float2 c = *(const float2*)&cw[(size_t)(256 + k) * D + c0];
        wk[k] = make_float4(g.x, g.y, c.x, c.y);
    }
    const float gb0 = gb[c0], gb1 = gb[c0 + 1];
    const float cb0 = cb[c0], cb1 = cb[c0 + 1];

    float acc0 = 0.0f, acc1 = 0.0f;

    int2 rec = (beg < end) ? sde[beg] : make_int2(0, 0);
    for (int i = beg; i < end; ++i) {
        const int dst = __builtin_amdgcn_readfirstlane(rec.x);
        const int eid = __builtin_amdgcn_readfirstlane(rec.y);
        int2 nrec = (i + 1 < end) ? sde[i + 1] : rec;   // prefetch next record

        // dst-side projections (L2/L3-resident: pb is 25.6 MB)
        unsigned int ugb = *(const unsigned int*)&pb[(size_t)dst * 256 + c0];
        unsigned int ucb = *(const unsigned int*)&pb[(size_t)dst * 256 + 128 + c0];

        // ef-dot with biases folded in: d = {dg0, dg1, dc0, dc1}
        const float* efr = &ef[(size_t)eid * DE];   // wave-uniform -> s_load
        float4 d = make_float4(gb0, gb1, cb0, cb1);
        #pragma unroll
        for (int k = 0; k < 10; ++k) {
            float e = efr[k];
            d.x = fmaf(e, wk[k].x, d.x);
            d.y = fmaf(e, wk[k].y, d.y);
            d.z = fmaf(e, wk[k].z, d.z);
            d.w = fmaf(e, wk[k].w, d.w);
        }
        float2 bg = bf2f(ugb), bc = bf2f(ucb);
        float g0 = ag.x + bg.x + d.x;
        float g1 = ag.y + bg.y + d.y;
        float x0 = ac.x + bc.x + d.z;
        float x1 = ac.y + bc.y + d.w;
        acc0 += fast_sigmoid(g0) * fast_softplus(x0);
        acc1 += fast_sigmoid(g1) * fast_softplus(x1);
        rec = nrec;
    }
    *(float2*)&agg[(size_t)n * D + c0] = make_float2(acc0, acc1);
}

__global__ __launch_bounds__(256) void col_stats(
    const float* __restrict__ agg, float* __restrict__ stats)
{
    const int t    = threadIdx.x;
    const int col  = t & 127;
    const int half = t >> 7;
    float s = 0.0f, s2 = 0.0f;
    for (int r = blockIdx.x * 2 + half; r < N_NODES; r += gridDim.x * 2) {
        float v = agg[(size_t)r * D + col];
        s += v; s2 += v * v;
    }
    atomicAdd(&stats[col], s);
    atomicAdd(&stats[128 + col], s2);
}

__global__ __launch_bounds__(256) void out_softplus(
    const float* __restrict__ h, const float* __restrict__ agg,
    const float* __restrict__ stats, const float* __restrict__ gamma,
    const float* __restrict__ beta, float* __restrict__ out)
{
    __shared__ float sc[128], bi[128];
    int t = threadIdx.x;
    if (t < 128) {
        const float inv_n = 1.0f / (float)N_NODES;
        float mean = stats[t] * inv_n;
        float var  = stats[128 + t] * inv_n - mean * mean;
        var = fmaxf(var, 0.0f);
        float rstd = rsqrtf(var + 1e-5f);
        float s = rstd * gamma[t];
        sc[t] = s;
        bi[t] = beta[t] - mean * s;
    }
    __syncthreads();
    int idx4 = blockIdx.x * 256 + t;
    int base = idx4 * 4;
    if (base < N_NODES * D) {
        float4 hv = *(const float4*)&h[base];
        float4 av = *(const float4*)&agg[base];
        int c = base & 127;
        float4 o;
        o.x = fast_softplus(hv.x + av.x * sc[c + 0] + bi[c + 0]);
        o.y = fast_softplus(hv.y + av.y * sc[c + 1] + bi[c + 1]);
        o.z = fast_softplus(hv.z + av.z * sc[c + 2] + bi[c + 2]);
        o.w = fast_softplus(hv.w + av.w * sc[c + 3] + bi[c + 3]);
        *(float4*)&out[base] = o;
    }
}

extern "C" void kernel_launch(void* const* d_in, const int* in_sizes, int n_in,
                              void* d_out, int out_size, void* d_ws, size_t ws_size,
                              hipStream_t stream) {
    const float* h     = (const float*)d_in[0];
    const int*   ei    = (const int*)  d_in[1];
    const float* ef    = (const float*)d_in[2];
    const float* gw    = (const float*)d_in[3];
    const float* gb    = (const float*)d_in[4];
    const float* cw    = (const float*)d_in[5];
    const float* cb    = (const float*)d_in[6];
    const float* gamma = (const float*)d_in[7];
    const float* beta  = (const float*)d_in[8];
    float* out = (float*)d_out;

    // Layout: [agg 25.6M][stats 1K][U: counts 3.2M+bsum -> later pb 25.6M][wp2][sde 6.4M][rp 200K]
    float*  agg    = (float*)d_ws;
    float*  stats  = agg + (size_t)N_NODES * D;
    int*    counts = (int*)(stats + 256);                    // U base
    int*    bsum   = counts + N_NODES * CSTRIDE;
    __bf16* pb     = (__bf16*)counts;                        // aliases U after csr_scatter
    char*   afterU = (char*)counts + (size_t)N_NODES * 256 * sizeof(__bf16);  // 25.6MB
    __bf16* wp2    = (__bf16*)afterU;                        // 128 KB
    int2*   sde    = (int2*)(wp2 + WP2_ELEMS);               // 6.4 MB
    int*    rp     = (int*)(sde + N_EDGES);                  // 200 KB
    __bf16* pa     = (__bf16*)d_out;                         // 25.6 MB scratch until final kernel
    // total ws ~= 57.95 MB (< 58.6 MB proven in R2)

    // zero only stats + counts (agg is plain-written by node_fuse now)
    hipMemsetAsync(stats, 0, 256 * sizeof(float) + (size_t)N_NODES * CSTRIDE * sizeof(int), stream);
    prep<<<3381, 256, 0, stream>>>(gw, cw, ei, wp2, counts);
    scan_partials<<<SCAN_BLOCKS, 256, 0, stream>>>(counts, bsum);
    scan_final<<<SCAN_BLOCKS, 256, 0, stream>>>(counts, bsum, rp);
    csr_scatter<<<N_EDGES / 256, 256, 0, stream>>>(ei, counts, sde);
    node_gemm<<<(N_NODES + 63) / 64, 512, 0, stream>>>(h, wp2, pa, pb);   // counts dead: pb safe
    node_fuse<<<N_NODES / 4, 256, 0, stream>>>(pa, pb, sde, ef, rp, gw, cw, gb, cb, agg);
    col_stats<<<784, 256, 0, stream>>>(agg, stats);
    out_softplus<<<N_NODES * D / 4 / 256, 256, 0, stream>>>(
        h, agg, stats, gamma, beta, out);
}